// Round 13
// baseline (609.148 us; speedup 1.0000x reference)
//
#include <hip/hip_runtime.h>

#define N_NODES 20000
#define N_EDGES 320000
#define X_DIM 128
#define EDGE_DIM 64
#define HIDDEN 256
#define N_GRAPHS 64
#define LAYERS 3

#define NPB 8     // nodes per block (node_proj)
#define EB 32     // edges per tile (edge_mfma)
#define NB 16     // dst nodes per block (edge_mfma, CSR) -> 1250 blocks, 32KB LDS
#define PSPLIT 8  // blocks per graph (pool)
#define NBLK ((N_NODES + 255) / 256)   // 79 scan blocks

typedef __attribute__((ext_vector_type(8))) short short8;
typedef __attribute__((ext_vector_type(4))) float floatx4;
typedef __attribute__((ext_vector_type(2))) unsigned int uint2v;

__device__ __forceinline__ unsigned short f2bf(float f) {
    union { float f; unsigned u; } v; v.f = f;
    return (unsigned short)((v.u + 0x7FFFu + ((v.u >> 16) & 1u)) >> 16);
}
__device__ __forceinline__ float bf2f(unsigned short u) {
    return __uint_as_float(((unsigned)u) << 16);
}

// ---------------- CSR build + pre-pass (once per launch) ----------------

__global__ __launch_bounds__(256) void deg_kernel(const int* __restrict__ ei,
                                                  int* __restrict__ deg)
{
    int e = blockIdx.x * 256 + threadIdx.x;
    if (e < N_EDGES) atomicAdd(&deg[ei[N_EDGES + e]], 1);
}

__global__ __launch_bounds__(256) void pscan_kernel(const int* __restrict__ deg,
                                                    int* __restrict__ rp,
                                                    int* __restrict__ bsum)
{
    __shared__ int buf[256];
    const int t = threadIdx.x;
    const int i = blockIdx.x * 256 + t;
    int v = (i < N_NODES) ? deg[i] : 0;
    buf[t] = v;
    __syncthreads();
    for (int off = 1; off < 256; off <<= 1) {
        int a = (t >= off) ? buf[t - off] : 0;
        __syncthreads();
        buf[t] += a;
        __syncthreads();
    }
    if (i < N_NODES) rp[i] = buf[t] - v;
    if (t == 255) bsum[blockIdx.x] = buf[255];
}

__global__ __launch_bounds__(128) void bscan_kernel(const int* __restrict__ bsum,
                                                    int* __restrict__ boff)
{
    __shared__ int buf[128];
    const int t = threadIdx.x;
    int v = (t < NBLK) ? bsum[t] : 0;
    buf[t] = v;
    __syncthreads();
    for (int off = 1; off < 128; off <<= 1) {
        int a = (t >= off) ? buf[t - off] : 0;
        __syncthreads();
        buf[t] += a;
        __syncthreads();
    }
    if (t < NBLK) boff[t] = buf[t] - v;
}

__global__ __launch_bounds__(256) void addoff_kernel(int* __restrict__ rp,
                                                     const int* __restrict__ boff)
{
    const int i = blockIdx.x * 256 + threadIdx.x;
    if (i < N_NODES) rp[i] += boff[blockIdx.x];
    if (i == 0) rp[N_NODES] = N_EDGES;
}

__global__ __launch_bounds__(256) void scatter_kernel(const int* __restrict__ ei,
                                                      const int* __restrict__ rp,
                                                      int* __restrict__ cursor,
                                                      int* __restrict__ perm)
{
    const int e = blockIdx.x * 256 + threadIdx.x;
    if (e < N_EDGES) {
        const int d = ei[N_EDGES + e];
        const int pos = atomicAdd(&cursor[d], 1);
        perm[rp[d] + pos] = e;
    }
}

// dst-sorted bf16 edge attrs + sorted src/dst index arrays
__global__ __launch_bounds__(256) void permute_kernel(
    const float* __restrict__ ea, const int* __restrict__ ei,
    const int* __restrict__ perm, unsigned short* __restrict__ eab,
    int* __restrict__ srcs, int* __restrict__ dsts)
{
    const int tid = blockIdx.x * 256 + threadIdx.x;
    const int e = tid >> 3, seg = tid & 7;
    const int p = perm[e];
    const float* sp = ea + (size_t)p * EDGE_DIM + seg * 8;
    const float4 v0 = *(const float4*)sp;
    const float4 v1 = *(const float4*)(sp + 4);
    short8 o;
    o[0] = (short)f2bf(v0.x); o[1] = (short)f2bf(v0.y);
    o[2] = (short)f2bf(v0.z); o[3] = (short)f2bf(v0.w);
    o[4] = (short)f2bf(v1.x); o[5] = (short)f2bf(v1.y);
    o[6] = (short)f2bf(v1.z); o[7] = (short)f2bf(v1.w);
    *(short8*)(eab + (size_t)e * EDGE_DIM + seg * 8) = o;
    if (seg == 0) { srcs[e] = ei[p]; dsts[e] = ei[N_EDGES + p]; }
}

// W [L][K][256] fp32 -> bf16 MFMA B-fragment order (all layers in one launch)
__global__ __launch_bounds__(256) void swizzle_kernel(const float* __restrict__ W,
                                                      unsigned short* __restrict__ out,
                                                      int KK, int total)
{
    const int gi = blockIdx.x * 256 + threadIdx.x;
    if (gi >= total) return;
    const int per = 8192 * KK;            // elements per layer
    const int l = gi / per, i = gi % per;
    const int j = i & 7, lane = (i >> 3) & 63, rem = i >> 9;
    const int kk = rem % KK, rem2 = rem / KK, nt = rem2 & 3, wvv = rem2 >> 2;
    const int n = wvv * 64 + nt * 16 + (lane & 15);
    const int k = kk * 32 + (lane >> 4) * 8 + j;
    out[(size_t)l * per + i] = f2bf(W[(size_t)l * per + k * HIDDEN + n]);
}

// ---------------- model kernels ----------------

// h[i] = x[i] @ xW + xb (fp32); also writes hbf
__global__ __launch_bounds__(256) void node_proj_kernel(
    const float* __restrict__ x, const float* __restrict__ W,
    const float* __restrict__ b, float* __restrict__ h,
    unsigned short* __restrict__ hbf)
{
    const int t = threadIdx.x;
    const int row0 = blockIdx.x * NPB;
    __shared__ float xs[NPB][X_DIM];
    for (int idx = t; idx < NPB * X_DIM; idx += 256)
        xs[idx / X_DIM][idx % X_DIM] = x[(size_t)row0 * X_DIM + idx];
    __syncthreads();
    float acc[NPB];
    const float bt = b[t];
#pragma unroll
    for (int r = 0; r < NPB; r++) acc[r] = bt;
    for (int k = 0; k < X_DIM; k++) {
        const float wv = W[k * HIDDEN + t];
#pragma unroll
        for (int r = 0; r < NPB; r++) acc[r] += xs[r][k] * wv;
    }
#pragma unroll
    for (int r = 0; r < NPB; r++) {
        const size_t idx = (size_t)(row0 + r) * HIDDEN + t;
        h[idx] = acc[r];
        hbf[idx] = f2bf(acc[r]);
    }
}

// edge phase, CSR per-node-block, barrier-free (r12 structure; NB=16 for
// 5 blocks/CU occupancy):
//   Abf[n] = bf16( h[n] + sum_{e->n} relu(hbf[src] + ea@W + b) )
// - agg[NB][256] fp32 in LDS, thread t owns column t -> plain += (no atomics)
// - register scan s over sorted dst, flushed to agg at uniform segment ends
// - srcs/dsts unclamped affine loads (padded arrays) -> batched s_load (r10)
// - msgT[ch][edge] (64B rows), physical byte = ch*64 + (off ^ s) with
//   s = ((ch>>1)&3)<<4 (in-row bits 4-5 only -> bijective; r11's cross-row
//   collision bug fixed in r12). Writer: 8x ds_write_b64/tile; reader: 4x
//   ds_read_b128. Both at the wave-throughput floor. Barrier-free
//   (same-wave DS ordering).
// - NB=16: agg 16KB + msgT 16KB = exactly 32KB -> 5 blocks/CU (163840/32768);
//   grid 1250 <= capacity 1280, all resident, 20 waves/CU (was 16 at NB=20).
__global__ __launch_bounds__(256, 4) void edge_mfma_kernel(
    const unsigned short* __restrict__ eab, const int* __restrict__ srcs,
    const int* __restrict__ dsts, const int* __restrict__ rowptr,
    const unsigned short* __restrict__ Ws, const float* __restrict__ b,
    const unsigned short* __restrict__ hbf, const float* __restrict__ h,
    unsigned short* __restrict__ Abf)
{
    const int t = threadIdx.x;
    const int lane = t & 63, wv = t >> 6, q = lane >> 4, m15 = lane & 15;
    const int row0 = blockIdx.x * NB;

    __shared__ float agg[NB][HIDDEN];                    // 16 KB, thread t owns column t
    __shared__ __align__(16) unsigned short msgT[256 * EB];  // 16 KB, [ch][edge], swizzled

    // zero agg (own column only -> no sync ever needed)
#pragma unroll
    for (int r = 0; r < NB; r++) agg[r][t] = 0.f;

    // loop-invariant B fragments + bias folded into acc init
    short8 bfr[4][2];
#pragma unroll
    for (int nt = 0; nt < 4; nt++)
#pragma unroll
        for (int kk = 0; kk < 2; kk++)
            bfr[nt][kk] = *(const short8*)(Ws + ((((wv * 4 + nt) * 2 + kk) * 64) + lane) * 8);
    float bv[4];
#pragma unroll
    for (int nt = 0; nt < 4; nt++) bv[nt] = b[wv * 64 + nt * 16 + m15];

    const int e_start = rowptr[row0];
    const int e_end   = rowptr[row0 + NB];
    const int cnt = e_end - e_start;
    const int ntiles = (cnt + EB - 1) >> 5;

    int prev = (cnt > 0) ? (dsts[e_start] - row0) : 0;   // uniform
    float s = 0.f;

    // loop-invariant swizzled addressing: ch&15 = m15, so s depends only on
    // bits 1-2 of m15 (write) / t (read) -> nt/wv-independent.
    char* const msgB = (char*)msgT;
    const unsigned wrow = (unsigned)((wv * 64 + m15) * (EB * 2));   // channel row base (nt adds 1024)
    const unsigned sw   = ((unsigned)((m15 >> 1) & 3)) << 4;        // in-row swizzle, bits 4-5
    const unsigned rrow = (unsigned)(t * (EB * 2));
    const unsigned sr   = ((unsigned)((t >> 1) & 3)) << 4;

    for (int tile = 0; tile < ntiles; tile++) {
        const int ebase = e_start + tile * EB;
        const int nin = min(EB, e_end - ebase);

        // A fragments first (oldest VMEM -> MFMA waits only on these)
        short8 a0[2], a1[2];
#pragma unroll
        for (int kk = 0; kk < 2; kk++) {
            a0[kk] = *(const short8*)(eab + (size_t)(ebase + m15) * EDGE_DIM + kk * 32 + q * 8);
            a1[kk] = *(const short8*)(eab + (size_t)(ebase + 16 + m15) * EDGE_DIM + kk * 32 + q * 8);
        }

        // gather h rows (own 64-ch slice); affine uniform srcs -> batched s_load
        unsigned short hv[EB];
#pragma unroll
        for (int e = 0; e < EB; e++) {
            const int se = srcs[ebase + e];
            hv[e] = hbf[(size_t)se * HIDDEN + t];
        }

        // MFMA: proj+bias; write 4 consecutive edges per channel as b64
#pragma unroll
        for (int mt = 0; mt < 2; mt++) {
            floatx4 acc[4];
#pragma unroll
            for (int nt = 0; nt < 4; nt++)
                acc[nt] = (floatx4){bv[nt], bv[nt], bv[nt], bv[nt]};
#pragma unroll
            for (int kk = 0; kk < 2; kk++) {
                const short8 a = mt ? a1[kk] : a0[kk];
#pragma unroll
                for (int nt = 0; nt < 4; nt++)
                    acc[nt] = __builtin_amdgcn_mfma_f32_16x16x32_bf16(a, bfr[nt][kk], acc[nt], 0, 0, 0);
            }
            // C layout: edge = mt*16 + q*4 + r, ch = wv*64 + nt*16 + m15
            // physical = rowbase(nt) + ((mt*32 + q*8) ^ sw); in-row, bijective
#pragma unroll
            for (int nt = 0; nt < 4; nt++) {
                uint2v w;
                w[0] = (unsigned)f2bf(acc[nt][0]) | ((unsigned)f2bf(acc[nt][1]) << 16);
                w[1] = (unsigned)f2bf(acc[nt][2]) | ((unsigned)f2bf(acc[nt][3]) << 16);
                *(uint2v*)(msgB + (wrow + (unsigned)(nt * 16 * EB * 2)
                                   + (((unsigned)(mt * 32 + q * 8)) ^ sw))) = w;
            }
        }

        // read own channel row: 4x ds_read_b128 = 32 edges (chunk j holds
        // logical edges 8j..8j+7: bits 0-3 untouched by the swizzle)
        short8 mr[4];
#pragma unroll
        for (int j = 0; j < 4; j++)
            mr[j] = *(const short8*)(msgB + (rrow + (((unsigned)(j * 16)) ^ sr)));

        // epilogue: register scan; dst compare + flush are wave-uniform (SGPR)
#pragma unroll
        for (int e = 0; e < EB; e++) {
            if (e < nin) {                                       // uniform
                const int d = dsts[ebase + e] - row0;
                if (d != prev) { agg[prev][t] += s; s = 0.f; prev = d; }
                const float m = bf2f((unsigned short)mr[e >> 3][e & 7]) + bf2f(hv[e]);
                s += m > 0.f ? m : 0.f;
            }
        }
    }
    if (cnt > 0) agg[prev][t] += s;

    // bulk writeout: A = bf16(h + agg); covers zero-degree rows for free
#pragma unroll
    for (int r = 0; r < NB; r++)
        Abf[(size_t)(row0 + r) * HIDDEN + t] =
            f2bf(h[(size_t)(row0 + r) * HIDDEN + t] + agg[r][t]);
}

// h = relu(relu(A@W1+b1)@W2+b2) with bf16 MFMA; A comes in bf16 from edge phase
__global__ __launch_bounds__(256) void mlp_mfma_kernel(
    const unsigned short* __restrict__ W1s, const float* __restrict__ b1,
    const unsigned short* __restrict__ W2s, const float* __restrict__ b2,
    const unsigned short* __restrict__ Abf,
    float* __restrict__ h, unsigned short* __restrict__ hbf)
{
    const int t = threadIdx.x;
    const int lane = t & 63, wv = t >> 6, q = lane >> 4, m15 = lane & 15;
    const int row0 = blockIdx.x * 32;
    __shared__ __align__(16) unsigned short zs[32][264];

    // stage A (bf16, vectorized: 4 x short8 per thread)
    const size_t base = (size_t)row0 * HIDDEN;
#pragma unroll
    for (int i = 0; i < 4; i++) {
        const int idx = i * 256 + t;            // short8 unit 0..1023
        const int row = idx >> 5, col = idx & 31;
        *(short8*)&zs[row][col * 8] = *(const short8*)(Abf + base + (size_t)idx * 8);
    }
    __syncthreads();

    float b1v[4], b2v[4];
#pragma unroll
    for (int nt = 0; nt < 4; nt++) {
        const int c = wv * 64 + nt * 16 + m15;
        b1v[nt] = b1[c]; b2v[nt] = b2[c];
    }

    floatx4 acc[2][4];
#pragma unroll
    for (int mt = 0; mt < 2; mt++)
#pragma unroll
        for (int nt = 0; nt < 4; nt++)
            acc[mt][nt] = (floatx4){0.f, 0.f, 0.f, 0.f};

    // GEMM1
#pragma unroll
    for (int kk = 0; kk < 8; kk++) {
        short8 bfr[4];
#pragma unroll
        for (int nt = 0; nt < 4; nt++)
            bfr[nt] = *(const short8*)(W1s + ((((wv * 4 + nt) * 8 + kk) * 64) + lane) * 8);
        const short8 a0 = *(const short8*)&zs[m15][kk * 32 + q * 8];
        const short8 a1 = *(const short8*)&zs[16 + m15][kk * 32 + q * 8];
#pragma unroll
        for (int nt = 0; nt < 4; nt++) {
            acc[0][nt] = __builtin_amdgcn_mfma_f32_16x16x32_bf16(a0, bfr[nt], acc[0][nt], 0, 0, 0);
            acc[1][nt] = __builtin_amdgcn_mfma_f32_16x16x32_bf16(a1, bfr[nt], acc[1][nt], 0, 0, 0);
        }
    }
    __syncthreads();
    // relu(acc+b1) -> zs (bf16)
#pragma unroll
    for (int mt = 0; mt < 2; mt++)
#pragma unroll
        for (int nt = 0; nt < 4; nt++)
#pragma unroll
            for (int r = 0; r < 4; r++) {
                const int row = mt * 16 + q * 4 + r, c = wv * 64 + nt * 16 + m15;
                const float v = acc[mt][nt][r] + b1v[nt];
                zs[row][c] = f2bf(v > 0.f ? v : 0.f);
            }
    __syncthreads();

#pragma unroll
    for (int mt = 0; mt < 2; mt++)
#pragma unroll
        for (int nt = 0; nt < 4; nt++)
            acc[mt][nt] = (floatx4){0.f, 0.f, 0.f, 0.f};

    // GEMM2
#pragma unroll
    for (int kk = 0; kk < 8; kk++) {
        short8 bfr[4];
#pragma unroll
        for (int nt = 0; nt < 4; nt++)
            bfr[nt] = *(const short8*)(W2s + ((((wv * 4 + nt) * 8 + kk) * 64) + lane) * 8);
        const short8 a0 = *(const short8*)&zs[m15][kk * 32 + q * 8];
        const short8 a1 = *(const short8*)&zs[16 + m15][kk * 32 + q * 8];
#pragma unroll
        for (int nt = 0; nt < 4; nt++) {
            acc[0][nt] = __builtin_amdgcn_mfma_f32_16x16x32_bf16(a0, bfr[nt], acc[0][nt], 0, 0, 0);
            acc[1][nt] = __builtin_amdgcn_mfma_f32_16x16x32_bf16(a1, bfr[nt], acc[1][nt], 0, 0, 0);
        }
    }
    // epilogue: h = relu(acc+b2), hbf = bf16(h)
#pragma unroll
    for (int mt = 0; mt < 2; mt++)
#pragma unroll
        for (int nt = 0; nt < 4; nt++)
#pragma unroll
            for (int r = 0; r < 4; r++) {
                const int row = mt * 16 + q * 4 + r, c = wv * 64 + nt * 16 + m15;
                float v = acc[mt][nt][r] + b2v[nt];
                v = v > 0.f ? v : 0.f;
                const size_t idx = (size_t)(row0 + row) * HIDDEN + c;
                h[idx] = v;
                hbf[idx] = f2bf(v);
            }
}

// parallel mean-pool partials: PSPLIT blocks per graph, atomicAdd into gsum
__global__ __launch_bounds__(256) void pool_kernel(
    const float* __restrict__ h, const int* __restrict__ bid,
    float* __restrict__ gsum)
{
    const int g = blockIdx.x / PSPLIT;
    const int part = blockIdx.x % PSPLIT;
    const int t = threadIdx.x;
    int lo = 0, hi = N_NODES;
    while (lo < hi) { int mid = (lo + hi) >> 1; if (bid[mid] < g) lo = mid + 1; else hi = mid; }
    const int start = lo;
    hi = N_NODES;
    while (lo < hi) { int mid = (lo + hi) >> 1; if (bid[mid] < g + 1) lo = mid + 1; else hi = mid; }
    const int end = lo;
    const int len = end - start;
    const int chunk = (len + PSPLIT - 1) / PSPLIT;
    const int s0 = start + part * chunk;
    const int s1 = min(s0 + chunk, end);
    if (s0 >= s1) return;
    float s = 0.f;
    for (int i = s0; i < s1; i++) s += h[(size_t)i * HIDDEN + t];
    atomicAdd(&gsum[g * HIDDEN + t], s);
}

// out = normalize(relu((gsum/cnt)@oW1+ob1)@oW2+ob2)
__global__ __launch_bounds__(256) void head_kernel(
    const float* __restrict__ gsum, const int* __restrict__ bid,
    const float* __restrict__ W1, const float* __restrict__ b1,
    const float* __restrict__ W2, const float* __restrict__ b2,
    float* __restrict__ out)
{
    const int g = blockIdx.x;
    const int t = threadIdx.x;
    __shared__ float gs[HIDDEN];
    __shared__ float t1[HIDDEN];
    __shared__ float red[256];
    int lo = 0, hi = N_NODES;
    while (lo < hi) { int mid = (lo + hi) >> 1; if (bid[mid] < g) lo = mid + 1; else hi = mid; }
    const int start = lo;
    hi = N_NODES;
    while (lo < hi) { int mid = (lo + hi) >> 1; if (bid[mid] < g + 1) lo = mid + 1; else hi = mid; }
    float cnt = (float)(lo - start);
    cnt = cnt > 1.f ? cnt : 1.f;
    gs[t] = gsum[g * HIDDEN + t] / cnt;
    __syncthreads();
    float acc = b1[t];
    for (int k = 0; k < HIDDEN; k++) acc += gs[k] * W1[k * HIDDEN + t];
    t1[t] = acc > 0.f ? acc : 0.f;
    __syncthreads();
    float acc2 = b2[t];
    for (int k = 0; k < HIDDEN; k++) acc2 += t1[k] * W2[k * HIDDEN + t];
    red[t] = acc2 * acc2;
    __syncthreads();
    for (int s = 128; s > 0; s >>= 1) {
        if (t < s) red[t] += red[t + s];
        __syncthreads();
    }
    float norm = sqrtf(red[0]);
    norm = norm > 1e-12f ? norm : 1e-12f;
    out[g * HIDDEN + t] = acc2 / norm;
}

extern "C" void kernel_launch(void* const* d_in, const int* in_sizes, int n_in,
                              void* d_out, int out_size, void* d_ws, size_t ws_size,
                              hipStream_t stream)
{
    const float* x   = (const float*)d_in[0];
    const int*   ei  = (const int*)d_in[1];
    const float* ea  = (const float*)d_in[2];
    const int*   bid = (const int*)d_in[3];
    const float* xW  = (const float*)d_in[4];
    const float* xb  = (const float*)d_in[5];
    const float* eW  = (const float*)d_in[6];
    const float* eb  = (const float*)d_in[7];
    const float* W1  = (const float*)d_in[8];
    const float* b1  = (const float*)d_in[9];
    const float* W2  = (const float*)d_in[10];
    const float* b2  = (const float*)d_in[11];
    const float* oW1 = (const float*)d_in[12];
    const float* ob1 = (const float*)d_in[13];
    const float* oW2 = (const float*)d_in[14];
    const float* ob2 = (const float*)d_in[15];
    float* out = (float*)d_out;

    // workspace layout (256B-aligned chunks)
    char* p = (char*)d_ws;
    auto alloc = [&](size_t bytes) { char* r = p; p += (bytes + 255) & ~(size_t)255; return r; };
    float* h     = (float*)alloc((size_t)N_NODES * HIDDEN * 4);
    float* gpool = (float*)alloc((size_t)N_GRAPHS * HIDDEN * 4);
    int* deg     = (int*)alloc(N_NODES * 4);
    int* rowptr  = (int*)alloc((N_NODES + 1) * 4);
    int* cursor  = (int*)alloc(N_NODES * 4);
    int* bsum    = (int*)alloc(NBLK * 4);
    int* boff    = (int*)alloc(NBLK * 4);
    int* perm    = (int*)alloc((size_t)N_EDGES * 4);
    int* srcs    = (int*)alloc((size_t)(N_EDGES + EB) * 4);   // +EB pad (unclamped reads)
    int* dsts    = (int*)alloc((size_t)(N_EDGES + EB) * 4);   // +EB pad
    unsigned short* hbf = (unsigned short*)alloc((size_t)N_NODES * HIDDEN * 2);
    unsigned short* Abf = (unsigned short*)alloc((size_t)N_NODES * HIDDEN * 2);
    unsigned short* eab = (unsigned short*)alloc((size_t)(N_EDGES + EB) * EDGE_DIM * 2); // +tile pad
    unsigned short* eWs = (unsigned short*)alloc((size_t)LAYERS * EDGE_DIM * HIDDEN * 2);
    unsigned short* W1s = (unsigned short*)alloc((size_t)LAYERS * HIDDEN * HIDDEN * 2);
    unsigned short* W2s = (unsigned short*)alloc((size_t)LAYERS * HIDDEN * HIDDEN * 2);

    // CSR build + dst-sorted bf16 edge data (reused across layers)
    hipMemsetAsync(deg, 0, N_NODES * sizeof(int), stream);
    hipMemsetAsync(cursor, 0, N_NODES * sizeof(int), stream);
    hipMemsetAsync(gpool, 0, N_GRAPHS * HIDDEN * sizeof(float), stream);
    hipMemsetAsync(srcs + N_EDGES, 0, EB * sizeof(int), stream);   // pad -> row 0 (safe)
    hipMemsetAsync(dsts + N_EDGES, 0, EB * sizeof(int), stream);   // pad loaded, never used
    deg_kernel<<<(N_EDGES + 255) / 256, 256, 0, stream>>>(ei, deg);
    pscan_kernel<<<NBLK, 256, 0, stream>>>(deg, rowptr, bsum);
    bscan_kernel<<<1, 128, 0, stream>>>(bsum, boff);
    addoff_kernel<<<NBLK, 256, 0, stream>>>(rowptr, boff);
    scatter_kernel<<<(N_EDGES + 255) / 256, 256, 0, stream>>>(ei, rowptr, cursor, perm);
    permute_kernel<<<(N_EDGES * 8) / 256, 256, 0, stream>>>(ea, ei, perm, eab, srcs, dsts);
    // weight swizzles: one launch per matrix type, all layers
    swizzle_kernel<<<(LAYERS * 8192 * 2 + 255) / 256, 256, 0, stream>>>(eW, eWs, 2, LAYERS * 8192 * 2);
    swizzle_kernel<<<(LAYERS * 8192 * 8 + 255) / 256, 256, 0, stream>>>(W1, W1s, 8, LAYERS * 8192 * 8);
    swizzle_kernel<<<(LAYERS * 8192 * 8 + 255) / 256, 256, 0, stream>>>(W2, W2s, 8, LAYERS * 8192 * 8);

    node_proj_kernel<<<N_NODES / NPB, 256, 0, stream>>>(x, xW, xb, h, hbf);
    for (int l = 0; l < LAYERS; l++) {
        edge_mfma_kernel<<<N_NODES / NB, 256, 0, stream>>>(
            eab, srcs, dsts, rowptr, eWs + (size_t)l * EDGE_DIM * HIDDEN,
            eb + l * HIDDEN, hbf, h, Abf);
        mlp_mfma_kernel<<<N_NODES / 32, 256, 0, stream>>>(
            W1s + (size_t)l * HIDDEN * HIDDEN, b1 + l * HIDDEN,
            W2s + (size_t)l * HIDDEN * HIDDEN, b2 + l * HIDDEN, Abf, h, hbf);
    }
    pool_kernel<<<N_GRAPHS * PSPLIT, 256, 0, stream>>>(h, bid, gpool);
    head_kernel<<<N_GRAPHS, 256, 0, stream>>>(gpool, bid, oW1, ob1, oW2, ob2, out);
}

// Round 14
// 551.233 us; speedup vs baseline: 1.1051x; 1.1051x over previous
//
#include <hip/hip_runtime.h>

#define N_NODES 20000
#define N_EDGES 320000
#define X_DIM 128
#define EDGE_DIM 64
#define HIDDEN 256
#define N_GRAPHS 64
#define LAYERS 3

#define NPB 8     // nodes per block (node_proj)
#define EB 32     // edges per tile (edge_mfma)
#define NB 20     // dst nodes per block (edge_mfma, CSR) -> exactly 1000 blocks
#define PSPLIT 8  // blocks per graph (pool)
#define NBLK ((N_NODES + 255) / 256)   // 79 scan blocks

typedef __attribute__((ext_vector_type(8))) short short8;
typedef __attribute__((ext_vector_type(4))) float floatx4;
typedef __attribute__((ext_vector_type(2))) unsigned int uint2v;

__device__ __forceinline__ unsigned short f2bf(float f) {
    union { float f; unsigned u; } v; v.f = f;
    return (unsigned short)((v.u + 0x7FFFu + ((v.u >> 16) & 1u)) >> 16);
}
__device__ __forceinline__ float bf2f(unsigned short u) {
    return __uint_as_float(((unsigned)u) << 16);
}

// ---------------- CSR build + pre-pass (once per launch) ----------------

__global__ __launch_bounds__(256) void deg_kernel(const int* __restrict__ ei,
                                                  int* __restrict__ deg)
{
    int e = blockIdx.x * 256 + threadIdx.x;
    if (e < N_EDGES) atomicAdd(&deg[ei[N_EDGES + e]], 1);
}

__global__ __launch_bounds__(256) void pscan_kernel(const int* __restrict__ deg,
                                                    int* __restrict__ rp,
                                                    int* __restrict__ bsum)
{
    __shared__ int buf[256];
    const int t = threadIdx.x;
    const int i = blockIdx.x * 256 + t;
    int v = (i < N_NODES) ? deg[i] : 0;
    buf[t] = v;
    __syncthreads();
    for (int off = 1; off < 256; off <<= 1) {
        int a = (t >= off) ? buf[t - off] : 0;
        __syncthreads();
        buf[t] += a;
        __syncthreads();
    }
    if (i < N_NODES) rp[i] = buf[t] - v;
    if (t == 255) bsum[blockIdx.x] = buf[255];
}

__global__ __launch_bounds__(128) void bscan_kernel(const int* __restrict__ bsum,
                                                    int* __restrict__ boff)
{
    __shared__ int buf[128];
    const int t = threadIdx.x;
    int v = (t < NBLK) ? bsum[t] : 0;
    buf[t] = v;
    __syncthreads();
    for (int off = 1; off < 128; off <<= 1) {
        int a = (t >= off) ? buf[t - off] : 0;
        __syncthreads();
        buf[t] += a;
        __syncthreads();
    }
    if (t < NBLK) boff[t] = buf[t] - v;
}

__global__ __launch_bounds__(256) void addoff_kernel(int* __restrict__ rp,
                                                     const int* __restrict__ boff)
{
    const int i = blockIdx.x * 256 + threadIdx.x;
    if (i < N_NODES) rp[i] += boff[blockIdx.x];
    if (i == 0) rp[N_NODES] = N_EDGES;
}

__global__ __launch_bounds__(256) void scatter_kernel(const int* __restrict__ ei,
                                                      const int* __restrict__ rp,
                                                      int* __restrict__ cursor,
                                                      int* __restrict__ perm)
{
    const int e = blockIdx.x * 256 + threadIdx.x;
    if (e < N_EDGES) {
        const int d = ei[N_EDGES + e];
        const int pos = atomicAdd(&cursor[d], 1);
        perm[rp[d] + pos] = e;
    }
}

// dst-sorted bf16 edge attrs + sorted src/dst index arrays
__global__ __launch_bounds__(256) void permute_kernel(
    const float* __restrict__ ea, const int* __restrict__ ei,
    const int* __restrict__ perm, unsigned short* __restrict__ eab,
    int* __restrict__ srcs, int* __restrict__ dsts)
{
    const int tid = blockIdx.x * 256 + threadIdx.x;
    const int e = tid >> 3, seg = tid & 7;
    const int p = perm[e];
    const float* sp = ea + (size_t)p * EDGE_DIM + seg * 8;
    const float4 v0 = *(const float4*)sp;
    const float4 v1 = *(const float4*)(sp + 4);
    short8 o;
    o[0] = (short)f2bf(v0.x); o[1] = (short)f2bf(v0.y);
    o[2] = (short)f2bf(v0.z); o[3] = (short)f2bf(v0.w);
    o[4] = (short)f2bf(v1.x); o[5] = (short)f2bf(v1.y);
    o[6] = (short)f2bf(v1.z); o[7] = (short)f2bf(v1.w);
    *(short8*)(eab + (size_t)e * EDGE_DIM + seg * 8) = o;
    if (seg == 0) { srcs[e] = ei[p]; dsts[e] = ei[N_EDGES + p]; }
}

// W [L][K][256] fp32 -> bf16 MFMA B-fragment order (all layers in one launch)
__global__ __launch_bounds__(256) void swizzle_kernel(const float* __restrict__ W,
                                                      unsigned short* __restrict__ out,
                                                      int KK, int total)
{
    const int gi = blockIdx.x * 256 + threadIdx.x;
    if (gi >= total) return;
    const int per = 8192 * KK;            // elements per layer
    const int l = gi / per, i = gi % per;
    const int j = i & 7, lane = (i >> 3) & 63, rem = i >> 9;
    const int kk = rem % KK, rem2 = rem / KK, nt = rem2 & 3, wvv = rem2 >> 2;
    const int n = wvv * 64 + nt * 16 + (lane & 15);
    const int k = kk * 32 + (lane >> 4) * 8 + j;
    out[(size_t)l * per + i] = f2bf(W[(size_t)l * per + k * HIDDEN + n]);
}

// ---------------- model kernels ----------------

// h[i] = x[i] @ xW + xb (fp32); also writes hbf
__global__ __launch_bounds__(256) void node_proj_kernel(
    const float* __restrict__ x, const float* __restrict__ W,
    const float* __restrict__ b, float* __restrict__ h,
    unsigned short* __restrict__ hbf)
{
    const int t = threadIdx.x;
    const int row0 = blockIdx.x * NPB;
    __shared__ float xs[NPB][X_DIM];
    for (int idx = t; idx < NPB * X_DIM; idx += 256)
        xs[idx / X_DIM][idx % X_DIM] = x[(size_t)row0 * X_DIM + idx];
    __syncthreads();
    float acc[NPB];
    const float bt = b[t];
#pragma unroll
    for (int r = 0; r < NPB; r++) acc[r] = bt;
    for (int k = 0; k < X_DIM; k++) {
        const float wv = W[k * HIDDEN + t];
#pragma unroll
        for (int r = 0; r < NPB; r++) acc[r] += xs[r][k] * wv;
    }
#pragma unroll
    for (int r = 0; r < NPB; r++) {
        const size_t idx = (size_t)(row0 + r) * HIDDEN + t;
        h[idx] = acc[r];
        hbf[idx] = f2bf(acc[r]);
    }
}

// edge phase, CSR per-node-block, barrier-free (r12 configuration — the
// measured optimum of this design space):
//   Abf[n] = bf16( h[n] + sum_{e->n} relu(hbf[src] + ea@W + b) )
// - agg[NB][256] fp32 in LDS, thread t owns column t -> plain += (no atomics;
//   LDS float atomicAdd = CAS loop, 4.5x regression r4)
// - register scan s over sorted dst, flushed to agg at uniform segment ends
// - srcs/dsts unclamped affine loads (padded arrays) -> batched s_load (r10:
//   min()-clamped form serialized 64 scalar loads in front of the gather)
// - msgT[ch][edge] (64B rows), physical byte = ch*64 + (off ^ s) with
//   s = ((ch>>1)&3)<<4 (in-row bits 4-5 only -> bijective per row; r11's
//   cross-row collision bug fixed in r12). Writer: 8x ds_write_b64/tile;
//   reader: 4x ds_read_b128. Both at the wave-throughput floor.
//   Barrier-free (same-wave DS ordering).
// - NB=20 -> 1000 blocks = full residency at 4 blk/CU (36.9 KB LDS), no
//   dribble. NB=16/32KB "5 blk/CU" is a trap: HW reserve keeps it at 4 ->
//   1250-block grid dribbles (r13, +58%). Half-tile msg serializes (r7).
//   2-deep register pipelining spills at the 128-VGPR cap (r8).
__global__ __launch_bounds__(256, 4) void edge_mfma_kernel(
    const unsigned short* __restrict__ eab, const int* __restrict__ srcs,
    const int* __restrict__ dsts, const int* __restrict__ rowptr,
    const unsigned short* __restrict__ Ws, const float* __restrict__ b,
    const unsigned short* __restrict__ hbf, const float* __restrict__ h,
    unsigned short* __restrict__ Abf)
{
    const int t = threadIdx.x;
    const int lane = t & 63, wv = t >> 6, q = lane >> 4, m15 = lane & 15;
    const int row0 = blockIdx.x * NB;

    __shared__ float agg[NB][HIDDEN];                    // 20 KB, thread t owns column t
    __shared__ __align__(16) unsigned short msgT[256 * EB];  // 16 KB, [ch][edge], swizzled

    // zero agg (own column only -> no sync ever needed)
#pragma unroll
    for (int r = 0; r < NB; r++) agg[r][t] = 0.f;

    // loop-invariant B fragments + bias folded into acc init
    short8 bfr[4][2];
#pragma unroll
    for (int nt = 0; nt < 4; nt++)
#pragma unroll
        for (int kk = 0; kk < 2; kk++)
            bfr[nt][kk] = *(const short8*)(Ws + ((((wv * 4 + nt) * 2 + kk) * 64) + lane) * 8);
    float bv[4];
#pragma unroll
    for (int nt = 0; nt < 4; nt++) bv[nt] = b[wv * 64 + nt * 16 + m15];

    const int e_start = rowptr[row0];
    const int e_end   = rowptr[row0 + NB];
    const int cnt = e_end - e_start;
    const int ntiles = (cnt + EB - 1) >> 5;

    int prev = (cnt > 0) ? (dsts[e_start] - row0) : 0;   // uniform
    float s = 0.f;

    // loop-invariant swizzled addressing: ch&15 = m15, so s depends only on
    // bits 1-2 of m15 (write) / t (read) -> nt/wv-independent.
    char* const msgB = (char*)msgT;
    const unsigned wrow = (unsigned)((wv * 64 + m15) * (EB * 2));   // channel row base (nt adds 1024)
    const unsigned sw   = ((unsigned)((m15 >> 1) & 3)) << 4;        // in-row swizzle, bits 4-5
    const unsigned rrow = (unsigned)(t * (EB * 2));
    const unsigned sr   = ((unsigned)((t >> 1) & 3)) << 4;

    for (int tile = 0; tile < ntiles; tile++) {
        const int ebase = e_start + tile * EB;
        const int nin = min(EB, e_end - ebase);

        // A fragments first (oldest VMEM -> MFMA waits only on these)
        short8 a0[2], a1[2];
#pragma unroll
        for (int kk = 0; kk < 2; kk++) {
            a0[kk] = *(const short8*)(eab + (size_t)(ebase + m15) * EDGE_DIM + kk * 32 + q * 8);
            a1[kk] = *(const short8*)(eab + (size_t)(ebase + 16 + m15) * EDGE_DIM + kk * 32 + q * 8);
        }

        // gather h rows (own 64-ch slice); affine uniform srcs -> batched s_load
        unsigned short hv[EB];
#pragma unroll
        for (int e = 0; e < EB; e++) {
            const int se = srcs[ebase + e];
            hv[e] = hbf[(size_t)se * HIDDEN + t];
        }

        // MFMA: proj+bias; write 4 consecutive edges per channel as b64
#pragma unroll
        for (int mt = 0; mt < 2; mt++) {
            floatx4 acc[4];
#pragma unroll
            for (int nt = 0; nt < 4; nt++)
                acc[nt] = (floatx4){bv[nt], bv[nt], bv[nt], bv[nt]};
#pragma unroll
            for (int kk = 0; kk < 2; kk++) {
                const short8 a = mt ? a1[kk] : a0[kk];
#pragma unroll
                for (int nt = 0; nt < 4; nt++)
                    acc[nt] = __builtin_amdgcn_mfma_f32_16x16x32_bf16(a, bfr[nt][kk], acc[nt], 0, 0, 0);
            }
            // C layout: edge = mt*16 + q*4 + r, ch = wv*64 + nt*16 + m15
            // physical = rowbase(nt) + ((mt*32 + q*8) ^ sw); in-row, bijective
#pragma unroll
            for (int nt = 0; nt < 4; nt++) {
                uint2v w;
                w[0] = (unsigned)f2bf(acc[nt][0]) | ((unsigned)f2bf(acc[nt][1]) << 16);
                w[1] = (unsigned)f2bf(acc[nt][2]) | ((unsigned)f2bf(acc[nt][3]) << 16);
                *(uint2v*)(msgB + (wrow + (unsigned)(nt * 16 * EB * 2)
                                   + (((unsigned)(mt * 32 + q * 8)) ^ sw))) = w;
            }
        }

        // read own channel row: 4x ds_read_b128 = 32 edges (chunk j holds
        // logical edges 8j..8j+7: bits 0-3 untouched by the swizzle)
        short8 mr[4];
#pragma unroll
        for (int j = 0; j < 4; j++)
            mr[j] = *(const short8*)(msgB + (rrow + (((unsigned)(j * 16)) ^ sr)));

        // epilogue: register scan; dst compare + flush are wave-uniform (SGPR)
#pragma unroll
        for (int e = 0; e < EB; e++) {
            if (e < nin) {                                       // uniform
                const int d = dsts[ebase + e] - row0;
                if (d != prev) { agg[prev][t] += s; s = 0.f; prev = d; }
                const float m = bf2f((unsigned short)mr[e >> 3][e & 7]) + bf2f(hv[e]);
                s += m > 0.f ? m : 0.f;
            }
        }
    }
    if (cnt > 0) agg[prev][t] += s;

    // bulk writeout: A = bf16(h + agg); covers zero-degree rows for free
#pragma unroll
    for (int r = 0; r < NB; r++)
        Abf[(size_t)(row0 + r) * HIDDEN + t] =
            f2bf(h[(size_t)(row0 + r) * HIDDEN + t] + agg[r][t]);
}

// h = relu(relu(A@W1+b1)@W2+b2) with bf16 MFMA; A comes in bf16 from edge phase
__global__ __launch_bounds__(256) void mlp_mfma_kernel(
    const unsigned short* __restrict__ W1s, const float* __restrict__ b1,
    const unsigned short* __restrict__ W2s, const float* __restrict__ b2,
    const unsigned short* __restrict__ Abf,
    float* __restrict__ h, unsigned short* __restrict__ hbf)
{
    const int t = threadIdx.x;
    const int lane = t & 63, wv = t >> 6, q = lane >> 4, m15 = lane & 15;
    const int row0 = blockIdx.x * 32;
    __shared__ __align__(16) unsigned short zs[32][264];

    // stage A (bf16, vectorized: 4 x short8 per thread)
    const size_t base = (size_t)row0 * HIDDEN;
#pragma unroll
    for (int i = 0; i < 4; i++) {
        const int idx = i * 256 + t;            // short8 unit 0..1023
        const int row = idx >> 5, col = idx & 31;
        *(short8*)&zs[row][col * 8] = *(const short8*)(Abf + base + (size_t)idx * 8);
    }
    __syncthreads();

    float b1v[4], b2v[4];
#pragma unroll
    for (int nt = 0; nt < 4; nt++) {
        const int c = wv * 64 + nt * 16 + m15;
        b1v[nt] = b1[c]; b2v[nt] = b2[c];
    }

    floatx4 acc[2][4];
#pragma unroll
    for (int mt = 0; mt < 2; mt++)
#pragma unroll
        for (int nt = 0; nt < 4; nt++)
            acc[mt][nt] = (floatx4){0.f, 0.f, 0.f, 0.f};

    // GEMM1
#pragma unroll
    for (int kk = 0; kk < 8; kk++) {
        short8 bfr[4];
#pragma unroll
        for (int nt = 0; nt < 4; nt++)
            bfr[nt] = *(const short8*)(W1s + ((((wv * 4 + nt) * 8 + kk) * 64) + lane) * 8);
        const short8 a0 = *(const short8*)&zs[m15][kk * 32 + q * 8];
        const short8 a1 = *(const short8*)&zs[16 + m15][kk * 32 + q * 8];
#pragma unroll
        for (int nt = 0; nt < 4; nt++) {
            acc[0][nt] = __builtin_amdgcn_mfma_f32_16x16x32_bf16(a0, bfr[nt], acc[0][nt], 0, 0, 0);
            acc[1][nt] = __builtin_amdgcn_mfma_f32_16x16x32_bf16(a1, bfr[nt], acc[1][nt], 0, 0, 0);
        }
    }
    __syncthreads();
    // relu(acc+b1) -> zs (bf16)
#pragma unroll
    for (int mt = 0; mt < 2; mt++)
#pragma unroll
        for (int nt = 0; nt < 4; nt++)
#pragma unroll
            for (int r = 0; r < 4; r++) {
                const int row = mt * 16 + q * 4 + r, c = wv * 64 + nt * 16 + m15;
                const float v = acc[mt][nt][r] + b1v[nt];
                zs[row][c] = f2bf(v > 0.f ? v : 0.f);
            }
    __syncthreads();

#pragma unroll
    for (int mt = 0; mt < 2; mt++)
#pragma unroll
        for (int nt = 0; nt < 4; nt++)
            acc[mt][nt] = (floatx4){0.f, 0.f, 0.f, 0.f};

    // GEMM2
#pragma unroll
    for (int kk = 0; kk < 8; kk++) {
        short8 bfr[4];
#pragma unroll
        for (int nt = 0; nt < 4; nt++)
            bfr[nt] = *(const short8*)(W2s + ((((wv * 4 + nt) * 8 + kk) * 64) + lane) * 8);
        const short8 a0 = *(const short8*)&zs[m15][kk * 32 + q * 8];
        const short8 a1 = *(const short8*)&zs[16 + m15][kk * 32 + q * 8];
#pragma unroll
        for (int nt = 0; nt < 4; nt++) {
            acc[0][nt] = __builtin_amdgcn_mfma_f32_16x16x32_bf16(a0, bfr[nt], acc[0][nt], 0, 0, 0);
            acc[1][nt] = __builtin_amdgcn_mfma_f32_16x16x32_bf16(a1, bfr[nt], acc[1][nt], 0, 0, 0);
        }
    }
    // epilogue: h = relu(acc+b2), hbf = bf16(h)
#pragma unroll
    for (int mt = 0; mt < 2; mt++)
#pragma unroll
        for (int nt = 0; nt < 4; nt++)
#pragma unroll
            for (int r = 0; r < 4; r++) {
                const int row = mt * 16 + q * 4 + r, c = wv * 64 + nt * 16 + m15;
                float v = acc[mt][nt][r] + b2v[nt];
                v = v > 0.f ? v : 0.f;
                const size_t idx = (size_t)(row0 + row) * HIDDEN + c;
                h[idx] = v;
                hbf[idx] = f2bf(v);
            }
}

// parallel mean-pool partials: PSPLIT blocks per graph, atomicAdd into gsum
__global__ __launch_bounds__(256) void pool_kernel(
    const float* __restrict__ h, const int* __restrict__ bid,
    float* __restrict__ gsum)
{
    const int g = blockIdx.x / PSPLIT;
    const int part = blockIdx.x % PSPLIT;
    const int t = threadIdx.x;
    int lo = 0, hi = N_NODES;
    while (lo < hi) { int mid = (lo + hi) >> 1; if (bid[mid] < g) lo = mid + 1; else hi = mid; }
    const int start = lo;
    hi = N_NODES;
    while (lo < hi) { int mid = (lo + hi) >> 1; if (bid[mid] < g + 1) lo = mid + 1; else hi = mid; }
    const int end = lo;
    const int len = end - start;
    const int chunk = (len + PSPLIT - 1) / PSPLIT;
    const int s0 = start + part * chunk;
    const int s1 = min(s0 + chunk, end);
    if (s0 >= s1) return;
    float s = 0.f;
    for (int i = s0; i < s1; i++) s += h[(size_t)i * HIDDEN + t];
    atomicAdd(&gsum[g * HIDDEN + t], s);
}

// out = normalize(relu((gsum/cnt)@oW1+ob1)@oW2+ob2)
__global__ __launch_bounds__(256) void head_kernel(
    const float* __restrict__ gsum, const int* __restrict__ bid,
    const float* __restrict__ W1, const float* __restrict__ b1,
    const float* __restrict__ W2, const float* __restrict__ b2,
    float* __restrict__ out)
{
    const int g = blockIdx.x;
    const int t = threadIdx.x;
    __shared__ float gs[HIDDEN];
    __shared__ float t1[HIDDEN];
    __shared__ float red[256];
    int lo = 0, hi = N_NODES;
    while (lo < hi) { int mid = (lo + hi) >> 1; if (bid[mid] < g) lo = mid + 1; else hi = mid; }
    const int start = lo;
    hi = N_NODES;
    while (lo < hi) { int mid = (lo + hi) >> 1; if (bid[mid] < g + 1) lo = mid + 1; else hi = mid; }
    float cnt = (float)(lo - start);
    cnt = cnt > 1.f ? cnt : 1.f;
    gs[t] = gsum[g * HIDDEN + t] / cnt;
    __syncthreads();
    float acc = b1[t];
    for (int k = 0; k < HIDDEN; k++) acc += gs[k] * W1[k * HIDDEN + t];
    t1[t] = acc > 0.f ? acc : 0.f;
    __syncthreads();
    float acc2 = b2[t];
    for (int k = 0; k < HIDDEN; k++) acc2 += t1[k] * W2[k * HIDDEN + t];
    red[t] = acc2 * acc2;
    __syncthreads();
    for (int s = 128; s > 0; s >>= 1) {
        if (t < s) red[t] += red[t + s];
        __syncthreads();
    }
    float norm = sqrtf(red[0]);
    norm = norm > 1e-12f ? norm : 1e-12f;
    out[g * HIDDEN + t] = acc2 / norm;
}

extern "C" void kernel_launch(void* const* d_in, const int* in_sizes, int n_in,
                              void* d_out, int out_size, void* d_ws, size_t ws_size,
                              hipStream_t stream)
{
    const float* x   = (const float*)d_in[0];
    const int*   ei  = (const int*)d_in[1];
    const float* ea  = (const float*)d_in[2];
    const int*   bid = (const int*)d_in[3];
    const float* xW  = (const float*)d_in[4];
    const float* xb  = (const float*)d_in[5];
    const float* eW  = (const float*)d_in[6];
    const float* eb  = (const float*)d_in[7];
    const float* W1  = (const float*)d_in[8];
    const float* b1  = (const float*)d_in[9];
    const float* W2  = (const float*)d_in[10];
    const float* b2  = (const float*)d_in[11];
    const float* oW1 = (const float*)d_in[12];
    const float* ob1 = (const float*)d_in[13];
    const float* oW2 = (const float*)d_in[14];
    const float* ob2 = (const float*)d_in[15];
    float* out = (float*)d_out;

    // workspace layout (256B-aligned chunks)
    char* p = (char*)d_ws;
    auto alloc = [&](size_t bytes) { char* r = p; p += (bytes + 255) & ~(size_t)255; return r; };
    float* h     = (float*)alloc((size_t)N_NODES * HIDDEN * 4);
    float* gpool = (float*)alloc((size_t)N_GRAPHS * HIDDEN * 4);
    int* deg     = (int*)alloc(N_NODES * 4);
    int* rowptr  = (int*)alloc((N_NODES + 1) * 4);
    int* cursor  = (int*)alloc(N_NODES * 4);
    int* bsum    = (int*)alloc(NBLK * 4);
    int* boff    = (int*)alloc(NBLK * 4);
    int* perm    = (int*)alloc((size_t)N_EDGES * 4);
    int* srcs    = (int*)alloc((size_t)(N_EDGES + EB) * 4);   // +EB pad (unclamped reads)
    int* dsts    = (int*)alloc((size_t)(N_EDGES + EB) * 4);   // +EB pad
    unsigned short* hbf = (unsigned short*)alloc((size_t)N_NODES * HIDDEN * 2);
    unsigned short* Abf = (unsigned short*)alloc((size_t)N_NODES * HIDDEN * 2);
    unsigned short* eab = (unsigned short*)alloc((size_t)(N_EDGES + EB) * EDGE_DIM * 2); // +tile pad
    unsigned short* eWs = (unsigned short*)alloc((size_t)LAYERS * EDGE_DIM * HIDDEN * 2);
    unsigned short* W1s = (unsigned short*)alloc((size_t)LAYERS * HIDDEN * HIDDEN * 2);
    unsigned short* W2s = (unsigned short*)alloc((size_t)LAYERS * HIDDEN * HIDDEN * 2);

    // CSR build + dst-sorted bf16 edge data (reused across layers)
    hipMemsetAsync(deg, 0, N_NODES * sizeof(int), stream);
    hipMemsetAsync(cursor, 0, N_NODES * sizeof(int), stream);
    hipMemsetAsync(gpool, 0, N_GRAPHS * HIDDEN * sizeof(float), stream);
    hipMemsetAsync(srcs + N_EDGES, 0, EB * sizeof(int), stream);   // pad -> row 0 (safe)
    hipMemsetAsync(dsts + N_EDGES, 0, EB * sizeof(int), stream);   // pad loaded, never used
    deg_kernel<<<(N_EDGES + 255) / 256, 256, 0, stream>>>(ei, deg);
    pscan_kernel<<<NBLK, 256, 0, stream>>>(deg, rowptr, bsum);
    bscan_kernel<<<1, 128, 0, stream>>>(bsum, boff);
    addoff_kernel<<<NBLK, 256, 0, stream>>>(rowptr, boff);
    scatter_kernel<<<(N_EDGES + 255) / 256, 256, 0, stream>>>(ei, rowptr, cursor, perm);
    permute_kernel<<<(N_EDGES * 8) / 256, 256, 0, stream>>>(ea, ei, perm, eab, srcs, dsts);
    // weight swizzles: one launch per matrix type, all layers
    swizzle_kernel<<<(LAYERS * 8192 * 2 + 255) / 256, 256, 0, stream>>>(eW, eWs, 2, LAYERS * 8192 * 2);
    swizzle_kernel<<<(LAYERS * 8192 * 8 + 255) / 256, 256, 0, stream>>>(W1, W1s, 8, LAYERS * 8192 * 8);
    swizzle_kernel<<<(LAYERS * 8192 * 8 + 255) / 256, 256, 0, stream>>>(W2, W2s, 8, LAYERS * 8192 * 8);

    node_proj_kernel<<<N_NODES / NPB, 256, 0, stream>>>(x, xW, xb, h, hbf);
    for (int l = 0; l < LAYERS; l++) {
        edge_mfma_kernel<<<N_NODES / NB, 256, 0, stream>>>(
            eab, srcs, dsts, rowptr, eWs + (size_t)l * EDGE_DIM * HIDDEN,
            eb + l * HIDDEN, hbf, h, Abf);
        mlp_mfma_kernel<<<N_NODES / 32, 256, 0, stream>>>(
            W1s + (size_t)l * HIDDEN * HIDDEN, b1 + l * HIDDEN,
            W2s + (size_t)l * HIDDEN * HIDDEN, b2 + l * HIDDEN, Abf, h, hbf);
    }
    pool_kernel<<<N_GRAPHS * PSPLIT, 256, 0, stream>>>(h, bid, gpool);
    head_kernel<<<N_GRAPHS, 256, 0, stream>>>(gpool, bid, oW1, ob1, oW2, ob2, out);
}

// Round 15
// 532.144 us; speedup vs baseline: 1.1447x; 1.0359x over previous
//
#include <hip/hip_runtime.h>

#define N_NODES 20000
#define N_EDGES 320000
#define X_DIM 128
#define EDGE_DIM 64
#define HIDDEN 256
#define N_GRAPHS 64
#define LAYERS 3

#define NPB 8     // nodes per block (node_proj)
#define EB 32     // edges per tile (edge_mfma)
#define NB 20     // dst nodes per block (edge_mfma, CSR) -> exactly 1000 blocks
#define MROWS 16  // rows per block (mlp_mfma) -> 1250 blocks, ~20 waves/CU
#define PSPLIT 8  // blocks per graph (pool)
#define NBLK ((N_NODES + 255) / 256)   // 79 scan blocks

typedef __attribute__((ext_vector_type(8))) short short8;
typedef __attribute__((ext_vector_type(4))) float floatx4;
typedef __attribute__((ext_vector_type(2))) unsigned int uint2v;

__device__ __forceinline__ unsigned short f2bf(float f) {
    union { float f; unsigned u; } v; v.f = f;
    return (unsigned short)((v.u + 0x7FFFu + ((v.u >> 16) & 1u)) >> 16);
}
__device__ __forceinline__ float bf2f(unsigned short u) {
    return __uint_as_float(((unsigned)u) << 16);
}

// ---------------- CSR build + pre-pass (once per launch) ----------------

__global__ __launch_bounds__(256) void deg_kernel(const int* __restrict__ ei,
                                                  int* __restrict__ deg)
{
    int e = blockIdx.x * 256 + threadIdx.x;
    if (e < N_EDGES) atomicAdd(&deg[ei[N_EDGES + e]], 1);
}

__global__ __launch_bounds__(256) void pscan_kernel(const int* __restrict__ deg,
                                                    int* __restrict__ rp,
                                                    int* __restrict__ bsum)
{
    __shared__ int buf[256];
    const int t = threadIdx.x;
    const int i = blockIdx.x * 256 + t;
    int v = (i < N_NODES) ? deg[i] : 0;
    buf[t] = v;
    __syncthreads();
    for (int off = 1; off < 256; off <<= 1) {
        int a = (t >= off) ? buf[t - off] : 0;
        __syncthreads();
        buf[t] += a;
        __syncthreads();
    }
    if (i < N_NODES) rp[i] = buf[t] - v;
    if (t == 255) bsum[blockIdx.x] = buf[255];
}

__global__ __launch_bounds__(128) void bscan_kernel(const int* __restrict__ bsum,
                                                    int* __restrict__ boff)
{
    __shared__ int buf[128];
    const int t = threadIdx.x;
    int v = (t < NBLK) ? bsum[t] : 0;
    buf[t] = v;
    __syncthreads();
    for (int off = 1; off < 128; off <<= 1) {
        int a = (t >= off) ? buf[t - off] : 0;
        __syncthreads();
        buf[t] += a;
        __syncthreads();
    }
    if (t < NBLK) boff[t] = buf[t] - v;
}

__global__ __launch_bounds__(256) void addoff_kernel(int* __restrict__ rp,
                                                     const int* __restrict__ boff)
{
    const int i = blockIdx.x * 256 + threadIdx.x;
    if (i < N_NODES) rp[i] += boff[blockIdx.x];
    if (i == 0) rp[N_NODES] = N_EDGES;
}

__global__ __launch_bounds__(256) void scatter_kernel(const int* __restrict__ ei,
                                                      const int* __restrict__ rp,
                                                      int* __restrict__ cursor,
                                                      int* __restrict__ perm)
{
    const int e = blockIdx.x * 256 + threadIdx.x;
    if (e < N_EDGES) {
        const int d = ei[N_EDGES + e];
        const int pos = atomicAdd(&cursor[d], 1);
        perm[rp[d] + pos] = e;
    }
}

// dst-sorted bf16 edge attrs + sorted src/dst index arrays
__global__ __launch_bounds__(256) void permute_kernel(
    const float* __restrict__ ea, const int* __restrict__ ei,
    const int* __restrict__ perm, unsigned short* __restrict__ eab,
    int* __restrict__ srcs, int* __restrict__ dsts)
{
    const int tid = blockIdx.x * 256 + threadIdx.x;
    const int e = tid >> 3, seg = tid & 7;
    const int p = perm[e];
    const float* sp = ea + (size_t)p * EDGE_DIM + seg * 8;
    const float4 v0 = *(const float4*)sp;
    const float4 v1 = *(const float4*)(sp + 4);
    short8 o;
    o[0] = (short)f2bf(v0.x); o[1] = (short)f2bf(v0.y);
    o[2] = (short)f2bf(v0.z); o[3] = (short)f2bf(v0.w);
    o[4] = (short)f2bf(v1.x); o[5] = (short)f2bf(v1.y);
    o[6] = (short)f2bf(v1.z); o[7] = (short)f2bf(v1.w);
    *(short8*)(eab + (size_t)e * EDGE_DIM + seg * 8) = o;
    if (seg == 0) { srcs[e] = ei[p]; dsts[e] = ei[N_EDGES + p]; }
}

// W [L][K][256] fp32 -> bf16 MFMA B-fragment order (all layers in one launch)
__global__ __launch_bounds__(256) void swizzle_kernel(const float* __restrict__ W,
                                                      unsigned short* __restrict__ out,
                                                      int KK, int total)
{
    const int gi = blockIdx.x * 256 + threadIdx.x;
    if (gi >= total) return;
    const int per = 8192 * KK;            // elements per layer
    const int l = gi / per, i = gi % per;
    const int j = i & 7, lane = (i >> 3) & 63, rem = i >> 9;
    const int kk = rem % KK, rem2 = rem / KK, nt = rem2 & 3, wvv = rem2 >> 2;
    const int n = wvv * 64 + nt * 16 + (lane & 15);
    const int k = kk * 32 + (lane >> 4) * 8 + j;
    out[(size_t)l * per + i] = f2bf(W[(size_t)l * per + k * HIDDEN + n]);
}

// ---------------- model kernels ----------------

// h[i] = x[i] @ xW + xb (fp32); also writes hbf
__global__ __launch_bounds__(256) void node_proj_kernel(
    const float* __restrict__ x, const float* __restrict__ W,
    const float* __restrict__ b, float* __restrict__ h,
    unsigned short* __restrict__ hbf)
{
    const int t = threadIdx.x;
    const int row0 = blockIdx.x * NPB;
    __shared__ float xs[NPB][X_DIM];
    for (int idx = t; idx < NPB * X_DIM; idx += 256)
        xs[idx / X_DIM][idx % X_DIM] = x[(size_t)row0 * X_DIM + idx];
    __syncthreads();
    float acc[NPB];
    const float bt = b[t];
#pragma unroll
    for (int r = 0; r < NPB; r++) acc[r] = bt;
    for (int k = 0; k < X_DIM; k++) {
        const float wv = W[k * HIDDEN + t];
#pragma unroll
        for (int r = 0; r < NPB; r++) acc[r] += xs[r][k] * wv;
    }
#pragma unroll
    for (int r = 0; r < NPB; r++) {
        const size_t idx = (size_t)(row0 + r) * HIDDEN + t;
        h[idx] = acc[r];
        hbf[idx] = f2bf(acc[r]);
    }
}

// edge phase, CSR per-node-block, barrier-free (r12 configuration — the
// measured optimum of this design space):
//   Abf[n] = bf16( h[n] + sum_{e->n} relu(hbf[src] + ea@W + b) )
// - agg[NB][256] fp32 in LDS, thread t owns column t -> plain += (no atomics;
//   LDS float atomicAdd = CAS loop, 4.5x regression r4)
// - register scan s over sorted dst, flushed to agg at uniform segment ends
// - srcs/dsts unclamped affine loads (padded arrays) -> batched s_load (r10)
// - msgT[ch][edge] (64B rows), physical byte = ch*64 + (off ^ s) with
//   s = ((ch>>1)&3)<<4 (in-row bits 4-5 only -> bijective per row).
//   Writer: 8x ds_write_b64/tile; reader: 4x ds_read_b128. Barrier-free.
// - NB=20 -> 1000 blocks = full residency at 4 blk/CU, no dribble.
//   (NB=16/32KB "5 blk/CU" is a trap: HW reserve keeps 4 -> dribble, r13.
//   Half-tile msg serializes, r7. 2-deep register pipelining spills, r8.)
__global__ __launch_bounds__(256, 4) void edge_mfma_kernel(
    const unsigned short* __restrict__ eab, const int* __restrict__ srcs,
    const int* __restrict__ dsts, const int* __restrict__ rowptr,
    const unsigned short* __restrict__ Ws, const float* __restrict__ b,
    const unsigned short* __restrict__ hbf, const float* __restrict__ h,
    unsigned short* __restrict__ Abf)
{
    const int t = threadIdx.x;
    const int lane = t & 63, wv = t >> 6, q = lane >> 4, m15 = lane & 15;
    const int row0 = blockIdx.x * NB;

    __shared__ float agg[NB][HIDDEN];                    // 20 KB, thread t owns column t
    __shared__ __align__(16) unsigned short msgT[256 * EB];  // 16 KB, [ch][edge], swizzled

    // zero agg (own column only -> no sync ever needed)
#pragma unroll
    for (int r = 0; r < NB; r++) agg[r][t] = 0.f;

    // loop-invariant B fragments + bias folded into acc init
    short8 bfr[4][2];
#pragma unroll
    for (int nt = 0; nt < 4; nt++)
#pragma unroll
        for (int kk = 0; kk < 2; kk++)
            bfr[nt][kk] = *(const short8*)(Ws + ((((wv * 4 + nt) * 2 + kk) * 64) + lane) * 8);
    float bv[4];
#pragma unroll
    for (int nt = 0; nt < 4; nt++) bv[nt] = b[wv * 64 + nt * 16 + m15];

    const int e_start = rowptr[row0];
    const int e_end   = rowptr[row0 + NB];
    const int cnt = e_end - e_start;
    const int ntiles = (cnt + EB - 1) >> 5;

    int prev = (cnt > 0) ? (dsts[e_start] - row0) : 0;   // uniform
    float s = 0.f;

    // loop-invariant swizzled addressing: ch&15 = m15, so s depends only on
    // bits 1-2 of m15 (write) / t (read) -> nt/wv-independent.
    char* const msgB = (char*)msgT;
    const unsigned wrow = (unsigned)((wv * 64 + m15) * (EB * 2));   // channel row base (nt adds 1024)
    const unsigned sw   = ((unsigned)((m15 >> 1) & 3)) << 4;        // in-row swizzle, bits 4-5
    const unsigned rrow = (unsigned)(t * (EB * 2));
    const unsigned sr   = ((unsigned)((t >> 1) & 3)) << 4;

    for (int tile = 0; tile < ntiles; tile++) {
        const int ebase = e_start + tile * EB;
        const int nin = min(EB, e_end - ebase);

        // A fragments first (oldest VMEM -> MFMA waits only on these)
        short8 a0[2], a1[2];
#pragma unroll
        for (int kk = 0; kk < 2; kk++) {
            a0[kk] = *(const short8*)(eab + (size_t)(ebase + m15) * EDGE_DIM + kk * 32 + q * 8);
            a1[kk] = *(const short8*)(eab + (size_t)(ebase + 16 + m15) * EDGE_DIM + kk * 32 + q * 8);
        }

        // gather h rows (own 64-ch slice); affine uniform srcs -> batched s_load
        unsigned short hv[EB];
#pragma unroll
        for (int e = 0; e < EB; e++) {
            const int se = srcs[ebase + e];
            hv[e] = hbf[(size_t)se * HIDDEN + t];
        }

        // MFMA: proj+bias; write 4 consecutive edges per channel as b64
#pragma unroll
        for (int mt = 0; mt < 2; mt++) {
            floatx4 acc[4];
#pragma unroll
            for (int nt = 0; nt < 4; nt++)
                acc[nt] = (floatx4){bv[nt], bv[nt], bv[nt], bv[nt]};
#pragma unroll
            for (int kk = 0; kk < 2; kk++) {
                const short8 a = mt ? a1[kk] : a0[kk];
#pragma unroll
                for (int nt = 0; nt < 4; nt++)
                    acc[nt] = __builtin_amdgcn_mfma_f32_16x16x32_bf16(a, bfr[nt][kk], acc[nt], 0, 0, 0);
            }
            // C layout: edge = mt*16 + q*4 + r, ch = wv*64 + nt*16 + m15
            // physical = rowbase(nt) + ((mt*32 + q*8) ^ sw); in-row, bijective
#pragma unroll
            for (int nt = 0; nt < 4; nt++) {
                uint2v w;
                w[0] = (unsigned)f2bf(acc[nt][0]) | ((unsigned)f2bf(acc[nt][1]) << 16);
                w[1] = (unsigned)f2bf(acc[nt][2]) | ((unsigned)f2bf(acc[nt][3]) << 16);
                *(uint2v*)(msgB + (wrow + (unsigned)(nt * 16 * EB * 2)
                                   + (((unsigned)(mt * 32 + q * 8)) ^ sw))) = w;
            }
        }

        // read own channel row: 4x ds_read_b128 = 32 edges (chunk j holds
        // logical edges 8j..8j+7: bits 0-3 untouched by the swizzle)
        short8 mr[4];
#pragma unroll
        for (int j = 0; j < 4; j++)
            mr[j] = *(const short8*)(msgB + (rrow + (((unsigned)(j * 16)) ^ sr)));

        // epilogue: register scan; dst compare + flush are wave-uniform (SGPR)
#pragma unroll
        for (int e = 0; e < EB; e++) {
            if (e < nin) {                                       // uniform
                const int d = dsts[ebase + e] - row0;
                if (d != prev) { agg[prev][t] += s; s = 0.f; prev = d; }
                const float m = bf2f((unsigned short)mr[e >> 3][e & 7]) + bf2f(hv[e]);
                s += m > 0.f ? m : 0.f;
            }
        }
    }
    if (cnt > 0) agg[prev][t] += s;

    // bulk writeout: A = bf16(h + agg); covers zero-degree rows for free
#pragma unroll
    for (int r = 0; r < NB; r++)
        Abf[(size_t)(row0 + r) * HIDDEN + t] =
            f2bf(h[(size_t)(row0 + r) * HIDDEN + t] + agg[r][t]);
}

// h = relu(relu(A@W1+b1)@W2+b2) with bf16 MFMA; A comes in bf16 from edge
// phase. MROWS=16 rows/block -> 1250 blocks (~20 waves/CU, 2x the 32-row
// version's latency hiding; the kernel is parallelism-bound: its MFMA work
// is <1 us aggregate while W-fragment L2 latency dominates). W traffic
// doubles but is L2-resident (512 KB working set). Same op order per row
// -> bit-identical output.
__global__ __launch_bounds__(256) void mlp_mfma_kernel(
    const unsigned short* __restrict__ W1s, const float* __restrict__ b1,
    const unsigned short* __restrict__ W2s, const float* __restrict__ b2,
    const unsigned short* __restrict__ Abf,
    float* __restrict__ h, unsigned short* __restrict__ hbf)
{
    const int t = threadIdx.x;
    const int lane = t & 63, wv = t >> 6, q = lane >> 4, m15 = lane & 15;
    const int row0 = blockIdx.x * MROWS;
    __shared__ __align__(16) unsigned short zs[MROWS][264];

    // stage A (bf16, vectorized: 2 x short8 per thread)
    const size_t base = (size_t)row0 * HIDDEN;
#pragma unroll
    for (int i = 0; i < 2; i++) {
        const int idx = i * 256 + t;            // short8 unit 0..511
        const int row = idx >> 5, col = idx & 31;
        *(short8*)&zs[row][col * 8] = *(const short8*)(Abf + base + (size_t)idx * 8);
    }
    __syncthreads();

    float b1v[4], b2v[4];
#pragma unroll
    for (int nt = 0; nt < 4; nt++) {
        const int c = wv * 64 + nt * 16 + m15;
        b1v[nt] = b1[c]; b2v[nt] = b2[c];
    }

    floatx4 acc[4];
#pragma unroll
    for (int nt = 0; nt < 4; nt++)
        acc[nt] = (floatx4){0.f, 0.f, 0.f, 0.f};

    // GEMM1 (16-row A-tile: single MFMA row-block)
#pragma unroll
    for (int kk = 0; kk < 8; kk++) {
        short8 bfr[4];
#pragma unroll
        for (int nt = 0; nt < 4; nt++)
            bfr[nt] = *(const short8*)(W1s + ((((wv * 4 + nt) * 8 + kk) * 64) + lane) * 8);
        const short8 a0 = *(const short8*)&zs[m15][kk * 32 + q * 8];
#pragma unroll
        for (int nt = 0; nt < 4; nt++)
            acc[nt] = __builtin_amdgcn_mfma_f32_16x16x32_bf16(a0, bfr[nt], acc[nt], 0, 0, 0);
    }
    __syncthreads();
    // relu(acc+b1) -> zs (bf16); row = q*4+r, c = wv*64+nt*16+m15
#pragma unroll
    for (int nt = 0; nt < 4; nt++)
#pragma unroll
        for (int r = 0; r < 4; r++) {
            const int row = q * 4 + r, c = wv * 64 + nt * 16 + m15;
            const float v = acc[nt][r] + b1v[nt];
            zs[row][c] = f2bf(v > 0.f ? v : 0.f);
        }
    __syncthreads();

#pragma unroll
    for (int nt = 0; nt < 4; nt++)
        acc[nt] = (floatx4){0.f, 0.f, 0.f, 0.f};

    // GEMM2
#pragma unroll
    for (int kk = 0; kk < 8; kk++) {
        short8 bfr[4];
#pragma unroll
        for (int nt = 0; nt < 4; nt++)
            bfr[nt] = *(const short8*)(W2s + ((((wv * 4 + nt) * 8 + kk) * 64) + lane) * 8);
        const short8 a0 = *(const short8*)&zs[m15][kk * 32 + q * 8];
#pragma unroll
        for (int nt = 0; nt < 4; nt++)
            acc[nt] = __builtin_amdgcn_mfma_f32_16x16x32_bf16(a0, bfr[nt], acc[nt], 0, 0, 0);
    }
    // epilogue: h = relu(acc+b2), hbf = bf16(h)
#pragma unroll
    for (int nt = 0; nt < 4; nt++)
#pragma unroll
        for (int r = 0; r < 4; r++) {
            const int row = q * 4 + r, c = wv * 64 + nt * 16 + m15;
            float v = acc[nt][r] + b2v[nt];
            v = v > 0.f ? v : 0.f;
            const size_t idx = (size_t)(row0 + row) * HIDDEN + c;
            h[idx] = v;
            hbf[idx] = f2bf(v);
        }
}

// parallel mean-pool partials: PSPLIT blocks per graph, atomicAdd into gsum
__global__ __launch_bounds__(256) void pool_kernel(
    const float* __restrict__ h, const int* __restrict__ bid,
    float* __restrict__ gsum)
{
    const int g = blockIdx.x / PSPLIT;
    const int part = blockIdx.x % PSPLIT;
    const int t = threadIdx.x;
    int lo = 0, hi = N_NODES;
    while (lo < hi) { int mid = (lo + hi) >> 1; if (bid[mid] < g) lo = mid + 1; else hi = mid; }
    const int start = lo;
    hi = N_NODES;
    while (lo < hi) { int mid = (lo + hi) >> 1; if (bid[mid] < g + 1) lo = mid + 1; else hi = mid; }
    const int end = lo;
    const int len = end - start;
    const int chunk = (len + PSPLIT - 1) / PSPLIT;
    const int s0 = start + part * chunk;
    const int s1 = min(s0 + chunk, end);
    if (s0 >= s1) return;
    float s = 0.f;
    for (int i = s0; i < s1; i++) s += h[(size_t)i * HIDDEN + t];
    atomicAdd(&gsum[g * HIDDEN + t], s);
}

// out = normalize(relu((gsum/cnt)@oW1+ob1)@oW2+ob2)
__global__ __launch_bounds__(256) void head_kernel(
    const float* __restrict__ gsum, const int* __restrict__ bid,
    const float* __restrict__ W1, const float* __restrict__ b1,
    const float* __restrict__ W2, const float* __restrict__ b2,
    float* __restrict__ out)
{
    const int g = blockIdx.x;
    const int t = threadIdx.x;
    __shared__ float gs[HIDDEN];
    __shared__ float t1[HIDDEN];
    __shared__ float red[256];
    int lo = 0, hi = N_NODES;
    while (lo < hi) { int mid = (lo + hi) >> 1; if (bid[mid] < g) lo = mid + 1; else hi = mid; }
    const int start = lo;
    hi = N_NODES;
    while (lo < hi) { int mid = (lo + hi) >> 1; if (bid[mid] < g + 1) lo = mid + 1; else hi = mid; }
    float cnt = (float)(lo - start);
    cnt = cnt > 1.f ? cnt : 1.f;
    gs[t] = gsum[g * HIDDEN + t] / cnt;
    __syncthreads();
    float acc = b1[t];
    for (int k = 0; k < HIDDEN; k++) acc += gs[k] * W1[k * HIDDEN + t];
    t1[t] = acc > 0.f ? acc : 0.f;
    __syncthreads();
    float acc2 = b2[t];
    for (int k = 0; k < HIDDEN; k++) acc2 += t1[k] * W2[k * HIDDEN + t];
    red[t] = acc2 * acc2;
    __syncthreads();
    for (int s = 128; s > 0; s >>= 1) {
        if (t < s) red[t] += red[t + s];
        __syncthreads();
    }
    float norm = sqrtf(red[0]);
    norm = norm > 1e-12f ? norm : 1e-12f;
    out[g * HIDDEN + t] = acc2 / norm;
}

extern "C" void kernel_launch(void* const* d_in, const int* in_sizes, int n_in,
                              void* d_out, int out_size, void* d_ws, size_t ws_size,
                              hipStream_t stream)
{
    const float* x   = (const float*)d_in[0];
    const int*   ei  = (const int*)d_in[1];
    const float* ea  = (const float*)d_in[2];
    const int*   bid = (const int*)d_in[3];
    const float* xW  = (const float*)d_in[4];
    const float* xb  = (const float*)d_in[5];
    const float* eW  = (const float*)d_in[6];
    const float* eb  = (const float*)d_in[7];
    const float* W1  = (const float*)d_in[8];
    const float* b1  = (const float*)d_in[9];
    const float* W2  = (const float*)d_in[10];
    const float* b2  = (const float*)d_in[11];
    const float* oW1 = (const float*)d_in[12];
    const float* ob1 = (const float*)d_in[13];
    const float* oW2 = (const float*)d_in[14];
    const float* ob2 = (const float*)d_in[15];
    float* out = (float*)d_out;

    // workspace layout (256B-aligned chunks)
    char* p = (char*)d_ws;
    auto alloc = [&](size_t bytes) { char* r = p; p += (bytes + 255) & ~(size_t)255; return r; };
    float* h     = (float*)alloc((size_t)N_NODES * HIDDEN * 4);
    float* gpool = (float*)alloc((size_t)N_GRAPHS * HIDDEN * 4);
    int* deg     = (int*)alloc(N_NODES * 4);
    int* rowptr  = (int*)alloc((N_NODES + 1) * 4);
    int* cursor  = (int*)alloc(N_NODES * 4);
    int* bsum    = (int*)alloc(NBLK * 4);
    int* boff    = (int*)alloc(NBLK * 4);
    int* perm    = (int*)alloc((size_t)N_EDGES * 4);
    int* srcs    = (int*)alloc((size_t)(N_EDGES + EB) * 4);   // +EB pad (unclamped reads)
    int* dsts    = (int*)alloc((size_t)(N_EDGES + EB) * 4);   // +EB pad
    unsigned short* hbf = (unsigned short*)alloc((size_t)N_NODES * HIDDEN * 2);
    unsigned short* Abf = (unsigned short*)alloc((size_t)N_NODES * HIDDEN * 2);
    unsigned short* eab = (unsigned short*)alloc((size_t)(N_EDGES + EB) * EDGE_DIM * 2); // +tile pad
    unsigned short* eWs = (unsigned short*)alloc((size_t)LAYERS * EDGE_DIM * HIDDEN * 2);
    unsigned short* W1s = (unsigned short*)alloc((size_t)LAYERS * HIDDEN * HIDDEN * 2);
    unsigned short* W2s = (unsigned short*)alloc((size_t)LAYERS * HIDDEN * HIDDEN * 2);

    // CSR build + dst-sorted bf16 edge data (reused across layers)
    hipMemsetAsync(deg, 0, N_NODES * sizeof(int), stream);
    hipMemsetAsync(cursor, 0, N_NODES * sizeof(int), stream);
    hipMemsetAsync(gpool, 0, N_GRAPHS * HIDDEN * sizeof(float), stream);
    hipMemsetAsync(srcs + N_EDGES, 0, EB * sizeof(int), stream);   // pad -> row 0 (safe)
    hipMemsetAsync(dsts + N_EDGES, 0, EB * sizeof(int), stream);   // pad loaded, never used
    deg_kernel<<<(N_EDGES + 255) / 256, 256, 0, stream>>>(ei, deg);
    pscan_kernel<<<NBLK, 256, 0, stream>>>(deg, rowptr, bsum);
    bscan_kernel<<<1, 128, 0, stream>>>(bsum, boff);
    addoff_kernel<<<NBLK, 256, 0, stream>>>(rowptr, boff);
    scatter_kernel<<<(N_EDGES + 255) / 256, 256, 0, stream>>>(ei, rowptr, cursor, perm);
    permute_kernel<<<(N_EDGES * 8) / 256, 256, 0, stream>>>(ea, ei, perm, eab, srcs, dsts);
    // weight swizzles: one launch per matrix type, all layers
    swizzle_kernel<<<(LAYERS * 8192 * 2 + 255) / 256, 256, 0, stream>>>(eW, eWs, 2, LAYERS * 8192 * 2);
    swizzle_kernel<<<(LAYERS * 8192 * 8 + 255) / 256, 256, 0, stream>>>(W1, W1s, 8, LAYERS * 8192 * 8);
    swizzle_kernel<<<(LAYERS * 8192 * 8 + 255) / 256, 256, 0, stream>>>(W2, W2s, 8, LAYERS * 8192 * 8);

    node_proj_kernel<<<N_NODES / NPB, 256, 0, stream>>>(x, xW, xb, h, hbf);
    for (int l = 0; l < LAYERS; l++) {
        edge_mfma_kernel<<<N_NODES / NB, 256, 0, stream>>>(
            eab, srcs, dsts, rowptr, eWs + (size_t)l * EDGE_DIM * HIDDEN,
            eb + l * HIDDEN, hbf, h, Abf);
        mlp_mfma_kernel<<<N_NODES / MROWS, 256, 0, stream>>>(
            W1s + (size_t)l * HIDDEN * HIDDEN, b1 + l * HIDDEN,
            W2s + (size_t)l * HIDDEN * HIDDEN, b2 + l * HIDDEN, Abf, h, hbf);
    }
    pool_kernel<<<N_GRAPHS * PSPLIT, 256, 0, stream>>>(h, bid, gpool);
    head_kernel<<<N_GRAPHS, 256, 0, stream>>>(gpool, bid, oW1, ob1, oW2, ob2, out);
}